// Round 5
// baseline (1551.476 us; speedup 1.0000x reference)
//
#include <hip/hip_runtime.h>

#define BS     4096
#define HIDDEN 2048
#define MAXR   16
#define NSLOT  8
#define NMOD   2
#define OUTW   8192
#define ROWS   8

typedef float f4 __attribute__((ext_vector_type(4)));

// ---------------------------------------------------------------------------
// Expand for ONE module, templated on rank-quads RQ = ceil(R/4) so breg
// indexing is compile-time (runtime-indexed ext_vector arrays -> scratch).
// Per 1024-col tile: cache B slab (RQ*4 x f4) in regs, stream 8 rows:
// uniform LDS inter reads (broadcast), 4*RQ f4 FMAs, one NT float4 store.
// ---------------------------------------------------------------------------
template<int RQ>
__device__ __forceinline__ void expand_mod(
    const float* __restrict__ B, const float* inter_s,
    float* __restrict__ out, int m, int s, int i0, int t)
{
    #pragma unroll 1
    for (int ct = 0; ct < 8; ++ct) {
        const int c0 = ct * 1024 + t * 4;
        const float* Bp = B + (size_t)(m * NSLOT + s) * MAXR * OUTW + c0;
        f4 breg[RQ * 4];
        #pragma unroll
        for (int r = 0; r < RQ * 4; ++r)
            breg[r] = *(const f4*)(Bp + (size_t)r * OUTW);
        #pragma unroll
        for (int j = 0; j < ROWS; ++j) {
            const float* ip = inter_s + j * MAXR;
            f4 acc = (f4)(0.f);
            #pragma unroll
            for (int rq = 0; rq < RQ; ++rq) {
                const f4 w = *(const f4*)(ip + 4 * rq);
                acc += w.x * breg[4*rq+0] + w.y * breg[4*rq+1]
                     + w.z * breg[4*rq+2] + w.w * breg[4*rq+3];
            }
            __builtin_nontemporal_store(acc,
                (f4*)(out + (size_t)(i0 + j) * (NMOD * OUTW) + (size_t)m * OUTW + c0));
        }
    }
}

// ---------------------------------------------------------------------------
// Fused LoRA, module-split: block = (slot s, module m, 8-row chunk).
// Grid 1024 -> 4 blocks/CU (16 waves/CU). hw&7 = s pins each slot to one
// XCD so its 512 KB B panel stays L2-resident; the two module-blocks of the
// same rows share x via L2/L3 (x = 32 MB, fully L3-resident).
// ROUND-5 CHANGES vs round 4 (which spilled: VGPR=256, scratch traffic):
//   - k-loop back to unroll 1 (unroll 2 doubled live xv/a set -> 256 VGPR)
//   - __launch_bounds__(256, 4): cap 128 VGPR (hand count: shrink ~95,
//     expand ~80 peak live) -> 4 waves/SIMD, no spill.
// ---------------------------------------------------------------------------
__global__ __launch_bounds__(256, 4) void lora_fused(
    const float* __restrict__ x,
    const float* __restrict__ A,
    const float* __restrict__ B,
    const int*   __restrict__ sorted_ids,
    const int*   __restrict__ slot_ranks,
    const int*   __restrict__ slot_offsets,
    float*       __restrict__ out)
{
    __shared__ float red[4 * 4 * ROWS * MAXR];   // 8 KiB (w,g,j,r)
    __shared__ float inter_s[ROWS * MAXR];       // 512 B

    const int t  = threadIdx.x;
    const int hw = blockIdx.x;
    const int s     = hw & 7;          // slot -> XCD
    const int m     = (hw >> 3) & 1;   // module
    const int chunk = hw >> 4;         // 0..63
    const int i0 = slot_offsets[s] + chunk * ROWS;
    const int R  = slot_ranks[s];

    int tok[ROWS];
    #pragma unroll
    for (int j = 0; j < ROWS; ++j) tok[j] = sorted_ids[i0 + j];  // uniform -> SGPR

    const int hq = t >> 2;   // 0..63 : h-quad
    const int q  = t & 3;    // r-quad (r = 4q..4q+3)

    f4 acc[ROWS];
    #pragma unroll
    for (int j = 0; j < ROWS; ++j) acc[j] = (f4)(0.f);

    const float* Ap_base = A + (size_t)(m * NSLOT + s) * (HIDDEN * MAXR);

    #pragma unroll 1
    for (int k = 0; k < 8; ++k) {
        f4 xv[ROWS];
        #pragma unroll
        for (int j = 0; j < ROWS; ++j)
            xv[j] = *(const f4*)(x + (size_t)tok[j] * HIDDEN + 256 * k + 4 * hq);
        const float* Ap = Ap_base + 4096 * k + 64 * hq + 4 * q;
        const f4 a0 = *(const f4*)(Ap);
        const f4 a1 = *(const f4*)(Ap + 16);
        const f4 a2 = *(const f4*)(Ap + 32);
        const f4 a3 = *(const f4*)(Ap + 48);
        #pragma unroll
        for (int j = 0; j < ROWS; ++j) {
            const f4 v = xv[j];
            acc[j] += v.x * a0 + v.y * a1 + v.z * a2 + v.w * a3;
        }
    }

    // butterfly over lane bits 2,3 (low bits of hq)
    #pragma unroll
    for (int j = 0; j < ROWS; ++j) {
        f4 a = acc[j];
        a.x += __shfl_xor(a.x, 4); a.y += __shfl_xor(a.y, 4);
        a.z += __shfl_xor(a.z, 4); a.w += __shfl_xor(a.w, 4);
        a.x += __shfl_xor(a.x, 8); a.y += __shfl_xor(a.y, 8);
        a.z += __shfl_xor(a.z, 8); a.w += __shfl_xor(a.w, 8);
        acc[j] = a;
    }

    if ((t & 12) == 0) {               // lanes 0-3 of each 16-group
        const int w = t >> 6, g = (t >> 4) & 3;
        #pragma unroll
        for (int j = 0; j < ROWS; ++j)
            *(f4*)(red + ((w * 4 + g) * ROWS + j) * MAXR + 4 * q) = acc[j];
    }
    __syncthreads();

    if (t < 128) {   // one (j, r) per thread; sum 16 partials; rank-mask
        const int j = t >> 4, r = t & 15;
        float v = 0.f;
        #pragma unroll
        for (int w = 0; w < 4; ++w)
            #pragma unroll
            for (int g = 0; g < 4; ++g)
                v += red[((w * 4 + g) * ROWS + j) * MAXR + r];
        if (r >= R) v = 0.f;           // rank mask -> expand needs no mask
        inter_s[j * MAXR + r] = v;
    }
    __syncthreads();

    const int rq = (R + 3) >> 2;
    switch (rq) {
        case 1:  expand_mod<1>(B, inter_s, out, m, s, i0, t); break;
        case 2:  expand_mod<2>(B, inter_s, out, m, s, i0, t); break;
        case 3:  expand_mod<3>(B, inter_s, out, m, s, i0, t); break;
        default: expand_mod<4>(B, inter_s, out, m, s, i0, t); break;
    }
}

extern "C" void kernel_launch(void* const* d_in, const int* in_sizes, int n_in,
                              void* d_out, int out_size, void* d_ws, size_t ws_size,
                              hipStream_t stream)
{
    const float* x            = (const float*)d_in[0];
    const float* A            = (const float*)d_in[1];
    const float* B            = (const float*)d_in[2];
    const int*   sorted_ids   = (const int*)d_in[3];
    const int*   slot_ranks   = (const int*)d_in[5];
    const int*   slot_offsets = (const int*)d_in[6];
    float*       out          = (float*)d_out;

    hipLaunchKernelGGL(lora_fused, dim3(BS / ROWS * NMOD), dim3(256), 0, stream,
                       x, A, B, sorted_ids, slot_ranks, slot_offsets, out);
}

// Round 6
// 659.312 us; speedup vs baseline: 2.3532x; 2.3532x over previous
//
#include <hip/hip_runtime.h>

#define BS     4096
#define HIDDEN 2048
#define MAXR   16
#define NSLOT  8
#define NMOD   2
#define OUTW   8192
#define ROWS   8

typedef float f4 __attribute__((ext_vector_type(4)));

// ---------------------------------------------------------------------------
// Expand for ONE module, templated on rank-quads RQ = ceil(R/4).
// LOW-PRESSURE VARIANT (r4 spilled at 256 VGPR, r5's forced 64-cap spilled
// worse): per 1024-col tile, loop rank-quads; each quad holds only 4 B
// f4-vectors (16 VGPR) live, accumulating into 8 per-row f4 accs (32 VGPR).
// Peak live ~60 VGPR. Same B traffic, uniform LDS inter reads (broadcast),
// one NT float4 store per row at the end.
// ---------------------------------------------------------------------------
template<int RQ>
__device__ __forceinline__ void expand_mod(
    const float* __restrict__ B, const float* inter_s,
    float* __restrict__ out, int m, int s, int i0, int t)
{
    #pragma unroll 1
    for (int ct = 0; ct < 8; ++ct) {
        const int c0 = ct * 1024 + t * 4;
        const float* Bp = B + (size_t)(m * NSLOT + s) * MAXR * OUTW + c0;

        f4 accj[ROWS];
        #pragma unroll
        for (int j = 0; j < ROWS; ++j) accj[j] = (f4)(0.f);

        #pragma unroll
        for (int rq = 0; rq < RQ; ++rq) {
            const f4 b0 = *(const f4*)(Bp + (size_t)(4 * rq + 0) * OUTW);
            const f4 b1 = *(const f4*)(Bp + (size_t)(4 * rq + 1) * OUTW);
            const f4 b2 = *(const f4*)(Bp + (size_t)(4 * rq + 2) * OUTW);
            const f4 b3 = *(const f4*)(Bp + (size_t)(4 * rq + 3) * OUTW);
            #pragma unroll
            for (int j = 0; j < ROWS; ++j) {
                const f4 w = *(const f4*)(inter_s + j * MAXR + 4 * rq);
                accj[j] += w.x * b0 + w.y * b1 + w.z * b2 + w.w * b3;
            }
        }
        #pragma unroll
        for (int j = 0; j < ROWS; ++j)
            __builtin_nontemporal_store(accj[j],
                (f4*)(out + (size_t)(i0 + j) * (NMOD * OUTW) + (size_t)m * OUTW + c0));
    }
}

// ---------------------------------------------------------------------------
// Fused LoRA, module-split: block = (slot s, module m, 8-row chunk).
// Grid 1024; hw&7 = s pins each slot's 512 KB B panel to one XCD's L2; the
// two module-blocks of the same rows share x via L2/L3 (x = 32 MB << L3).
// NO min-waves launch bound (r5's (256,4) forced VGPR=64 -> 2.1 GB scratch);
// regalloc lands naturally, peak live ~85 (shrink) / ~60 (expand).
// Phase 1 (shrink, own module): t = (hq=t>>2, q=t&3); per k-step 8 f4
// x-loads (4 lanes share addr -> one 256B fetch) + 4 f4 A-loads + 128 FMAs.
// Butterfly (lane bits 2,3) -> 8KB red LDS -> rank-masked inter (512B LDS).
// Phase 2: rank-templated low-pressure expand, NT stores.
// ---------------------------------------------------------------------------
__global__ __launch_bounds__(256) void lora_fused(
    const float* __restrict__ x,
    const float* __restrict__ A,
    const float* __restrict__ B,
    const int*   __restrict__ sorted_ids,
    const int*   __restrict__ slot_ranks,
    const int*   __restrict__ slot_offsets,
    float*       __restrict__ out)
{
    __shared__ float red[4 * 4 * ROWS * MAXR];   // 8 KiB (w,g,j,r)
    __shared__ float inter_s[ROWS * MAXR];       // 512 B

    const int t  = threadIdx.x;
    const int hw = blockIdx.x;
    const int s     = hw & 7;          // slot -> XCD
    const int m     = (hw >> 3) & 1;   // module
    const int chunk = hw >> 4;         // 0..63
    const int i0 = slot_offsets[s] + chunk * ROWS;
    const int R  = slot_ranks[s];

    int tok[ROWS];
    #pragma unroll
    for (int j = 0; j < ROWS; ++j) tok[j] = sorted_ids[i0 + j];  // uniform -> SGPR

    const int hq = t >> 2;   // 0..63 : h-quad
    const int q  = t & 3;    // r-quad (r = 4q..4q+3)

    f4 acc[ROWS];
    #pragma unroll
    for (int j = 0; j < ROWS; ++j) acc[j] = (f4)(0.f);

    const float* Ap_base = A + (size_t)(m * NSLOT + s) * (HIDDEN * MAXR);

    #pragma unroll 1
    for (int k = 0; k < 8; ++k) {
        f4 xv[ROWS];
        #pragma unroll
        for (int j = 0; j < ROWS; ++j)
            xv[j] = *(const f4*)(x + (size_t)tok[j] * HIDDEN + 256 * k + 4 * hq);
        const float* Ap = Ap_base + 4096 * k + 64 * hq + 4 * q;
        const f4 a0 = *(const f4*)(Ap);
        const f4 a1 = *(const f4*)(Ap + 16);
        const f4 a2 = *(const f4*)(Ap + 32);
        const f4 a3 = *(const f4*)(Ap + 48);
        #pragma unroll
        for (int j = 0; j < ROWS; ++j) {
            const f4 v = xv[j];
            acc[j] += v.x * a0 + v.y * a1 + v.z * a2 + v.w * a3;
        }
    }

    // butterfly over lane bits 2,3 (low bits of hq)
    #pragma unroll
    for (int j = 0; j < ROWS; ++j) {
        f4 a = acc[j];
        a.x += __shfl_xor(a.x, 4); a.y += __shfl_xor(a.y, 4);
        a.z += __shfl_xor(a.z, 4); a.w += __shfl_xor(a.w, 4);
        a.x += __shfl_xor(a.x, 8); a.y += __shfl_xor(a.y, 8);
        a.z += __shfl_xor(a.z, 8); a.w += __shfl_xor(a.w, 8);
        acc[j] = a;
    }

    if ((t & 12) == 0) {               // lanes 0-3 of each 16-group
        const int w = t >> 6, g = (t >> 4) & 3;
        #pragma unroll
        for (int j = 0; j < ROWS; ++j)
            *(f4*)(red + ((w * 4 + g) * ROWS + j) * MAXR + 4 * q) = acc[j];
    }
    __syncthreads();

    if (t < 128) {   // one (j, r) per thread; sum 16 partials; rank-mask
        const int j = t >> 4, r = t & 15;
        float v = 0.f;
        #pragma unroll
        for (int w = 0; w < 4; ++w)
            #pragma unroll
            for (int g = 0; g < 4; ++g)
                v += red[((w * 4 + g) * ROWS + j) * MAXR + r];
        if (r >= R) v = 0.f;           // rank mask -> expand needs no mask
        inter_s[j * MAXR + r] = v;
    }
    __syncthreads();

    const int rq = (R + 3) >> 2;
    switch (rq) {
        case 1:  expand_mod<1>(B, inter_s, out, m, s, i0, t); break;
        case 2:  expand_mod<2>(B, inter_s, out, m, s, i0, t); break;
        case 3:  expand_mod<3>(B, inter_s, out, m, s, i0, t); break;
        default: expand_mod<4>(B, inter_s, out, m, s, i0, t); break;
    }
}

extern "C" void kernel_launch(void* const* d_in, const int* in_sizes, int n_in,
                              void* d_out, int out_size, void* d_ws, size_t ws_size,
                              hipStream_t stream)
{
    const float* x            = (const float*)d_in[0];
    const float* A            = (const float*)d_in[1];
    const float* B            = (const float*)d_in[2];
    const int*   sorted_ids   = (const int*)d_in[3];
    const int*   slot_ranks   = (const int*)d_in[5];
    const int*   slot_offsets = (const int*)d_in[6];
    float*       out          = (float*)d_out;

    hipLaunchKernelGGL(lora_fused, dim3(BS / ROWS * NMOD), dim3(256), 0, stream,
                       x, A, B, sorted_ids, slot_ranks, slot_offsets, out);
}

// Round 7
// 499.133 us; speedup vs baseline: 3.1083x; 1.3209x over previous
//
#include <hip/hip_runtime.h>

#define BS     4096
#define HIDDEN 2048
#define MAXR   16
#define NSLOT  8
#define NMOD   2
#define OUTW   8192
#define ROWS   8

typedef float f4 __attribute__((ext_vector_type(4)));

// ---------------------------------------------------------------------------
// Expand phase (r3-proven body), templated on rank-quads RQ = ceil(R/4) so
// breg indexing stays compile-time. This round: each block covers only 8 of
// the 16 (module, col-tile) pairs, selected by colhalf (0: m=0, 1: m=1).
// Per tile: cache B slab (RQ*4 x f4) in regs, stream 8 rows: uniform LDS
// inter reads (broadcast), 4*RQ f4 FMAs, one NT float4 store.
// ---------------------------------------------------------------------------
template<int RQ>
__device__ __forceinline__ void expand_tiles(
    const float* __restrict__ B, const float* inter_s,
    float* __restrict__ out, int s, int i0, int t, int colhalf)
{
    #pragma unroll 1
    for (int ct = 0; ct < 8; ++ct) {
        const int ctt = colhalf * 8 + ct;
        const int m   = ctt >> 3;
        const int c0  = (ctt & 7) * 1024 + t * 4;
        const float* Bp = B + ((size_t)(m * NSLOT + s) * MAXR) * OUTW + c0;
        f4 breg[RQ * 4];
        #pragma unroll
        for (int r = 0; r < RQ * 4; ++r)
            breg[r] = *(const f4*)(Bp + (size_t)r * OUTW);
        #pragma unroll
        for (int j = 0; j < ROWS; ++j) {
            const float* ip = inter_s + (m * ROWS + j) * MAXR;
            f4 acc = (f4)(0.f);
            #pragma unroll
            for (int rq = 0; rq < RQ; ++rq) {
                const f4 w = *(const f4*)(ip + 4 * rq);
                acc += w.x * breg[4*rq+0] + w.y * breg[4*rq+1]
                     + w.z * breg[4*rq+2] + w.w * breg[4*rq+3];
            }
            __builtin_nontemporal_store(acc,
                (f4*)(out + (size_t)(i0 + j) * (NMOD * OUTW) + (size_t)m * OUTW + c0));
        }
    }
}

// ---------------------------------------------------------------------------
// Fused LoRA — r3 structure VERBATIM (it compiled clean at 65 us; every
// module-split restructure r4-r6 hit a 256-VGPR scratch-spill codegen), with
// ONE change: grid 512 -> 1024 via a column-half split. Each block runs the
// full r3 shrink (both modules; redundant but keeps r3's regalloc) and
// expands 8 of 16 tiles. 4 blocks/CU (16 waves/CU) hides shrink x-load
// latency and per-tile B-slab load bursts; phases stagger across blocks.
// Swizzle (hw&7)*128 + hw>>3 pins each slot's blocks (and its 1 MB B panel)
// to one XCD's L2, as in r3.
// ---------------------------------------------------------------------------
__global__ __launch_bounds__(256) void lora_fused(
    const float* __restrict__ x,
    const float* __restrict__ A,
    const float* __restrict__ B,
    const int*   __restrict__ sorted_ids,
    const int*   __restrict__ slot_ranks,
    const int*   __restrict__ slot_offsets,
    float*       __restrict__ out)
{
    __shared__ float red[NMOD * 4 * 4 * ROWS * MAXR];   // 16 KiB (m,w,g,j,r)
    __shared__ float inter_s[NMOD * ROWS * MAXR];       // 1 KiB

    const int t = threadIdx.x;
    // slot->XCD swizzle over 1024 blocks: hw -> logical (hw%8)*128 + hw/8
    const int bid2    = (blockIdx.x & 7) * 128 + (blockIdx.x >> 3);  // [0,1024)
    const int w2      = bid2 & 127;
    const int chunk   = w2 >> 1;          // 0..63 within slot
    const int colhalf = w2 & 1;           // which 8-tile half
    const int i0      = ((bid2 >> 7) * 64 + chunk) * ROWS;

    int s = 0;
    #pragma unroll
    for (int k = 1; k < NSLOT; ++k) if (i0 >= slot_offsets[k]) s = k;

    int tok[ROWS];
    #pragma unroll
    for (int j = 0; j < ROWS; ++j) tok[j] = sorted_ids[i0 + j];   // uniform -> s_load

    const int hq = t >> 2;   // 0..63 : h-quad
    const int q  = t & 3;    // r-quad (r = 4q..4q+3)

    f4 acc[NMOD][ROWS];
    #pragma unroll
    for (int m = 0; m < NMOD; ++m)
        #pragma unroll
        for (int j = 0; j < ROWS; ++j) acc[m][j] = (f4)(0.f);

    #pragma unroll 1
    for (int k = 0; k < 8; ++k) {
        f4 xv[ROWS];
        #pragma unroll
        for (int j = 0; j < ROWS; ++j)
            xv[j] = *(const f4*)(x + (size_t)tok[j] * HIDDEN + 256 * k + 4 * hq);
        #pragma unroll
        for (int m = 0; m < NMOD; ++m) {
            const float* Ap = A + (size_t)(m * NSLOT + s) * (HIDDEN * MAXR)
                                + 4096 * k + 64 * hq + 4 * q;
            const f4 a0 = *(const f4*)(Ap);
            const f4 a1 = *(const f4*)(Ap + 16);
            const f4 a2 = *(const f4*)(Ap + 32);
            const f4 a3 = *(const f4*)(Ap + 48);
            #pragma unroll
            for (int j = 0; j < ROWS; ++j) {
                const f4 v = xv[j];
                acc[m][j] += v.x * a0 + v.y * a1 + v.z * a2 + v.w * a3;
            }
        }
    }

    // butterfly over lane bits 2,3 (low bits of hq)
    #pragma unroll
    for (int m = 0; m < NMOD; ++m)
        #pragma unroll
        for (int j = 0; j < ROWS; ++j) {
            f4 a = acc[m][j];
            a.x += __shfl_xor(a.x, 4); a.y += __shfl_xor(a.y, 4);
            a.z += __shfl_xor(a.z, 4); a.w += __shfl_xor(a.w, 4);
            a.x += __shfl_xor(a.x, 8); a.y += __shfl_xor(a.y, 8);
            a.z += __shfl_xor(a.z, 8); a.w += __shfl_xor(a.w, 8);
            acc[m][j] = a;
        }

    if ((t & 12) == 0) {
        const int w = t >> 6, g = (t >> 4) & 3;
        #pragma unroll
        for (int m = 0; m < NMOD; ++m)
            #pragma unroll
            for (int j = 0; j < ROWS; ++j)
                *(f4*)(red + (((m * 4 + w) * 4 + g) * ROWS + j) * MAXR + 4 * q) = acc[m][j];
    }
    __syncthreads();

    {   // final reduce: one (m, j, r) per thread; rank-mask; write LDS inter
        const int m = t >> 7, j = (t >> 4) & 7, r = t & 15;
        float v = 0.f;
        #pragma unroll
        for (int w = 0; w < 4; ++w)
            #pragma unroll
            for (int g = 0; g < 4; ++g)
                v += red[(((m * 4 + w) * 4 + g) * ROWS + j) * MAXR + r];
        if (r >= slot_ranks[s]) v = 0.f;
        inter_s[(m * ROWS + j) * MAXR + r] = v;
    }
    __syncthreads();

    const int rq = (slot_ranks[s] + 3) >> 2;
    switch (rq) {
        case 1:  expand_tiles<1>(B, inter_s, out, s, i0, t, colhalf); break;
        case 2:  expand_tiles<2>(B, inter_s, out, s, i0, t, colhalf); break;
        case 3:  expand_tiles<3>(B, inter_s, out, s, i0, t, colhalf); break;
        default: expand_tiles<4>(B, inter_s, out, s, i0, t, colhalf); break;
    }
}

extern "C" void kernel_launch(void* const* d_in, const int* in_sizes, int n_in,
                              void* d_out, int out_size, void* d_ws, size_t ws_size,
                              hipStream_t stream)
{
    const float* x            = (const float*)d_in[0];
    const float* A            = (const float*)d_in[1];
    const float* B            = (const float*)d_in[2];
    const int*   sorted_ids   = (const int*)d_in[3];
    const int*   slot_ranks   = (const int*)d_in[5];
    const int*   slot_offsets = (const int*)d_in[6];
    float*       out          = (float*)d_out;

    hipLaunchKernelGGL(lora_fused, dim3(BS / ROWS * NMOD), dim3(256), 0, stream,
                       x, A, B, sorted_ids, slot_ranks, slot_offsets, out);
}

// Round 8
// 86.005 us; speedup vs baseline: 18.0394x; 5.8036x over previous
//
#include <hip/hip_runtime.h>

#define BS     4096
#define HIDDEN 2048
#define MAXR   16
#define NSLOT  8
#define NMOD   2
#define OUTW   8192
#define ROWS   8

typedef float f4 __attribute__((ext_vector_type(4)));

// ---------------------------------------------------------------------------
// Kernel 1: shrink, single-module blocks. Grid 1024 = (m, 8-row chunk).
// inter[m][i][r] = sum_h x[sorted_ids[i]][h] * A[m,s,h,r], rank-masked.
// Thread t: hq=t>>2 (h-quad), q=t&3 (r-quad). Per k-step: 8 f4 x-loads
// (4 lanes share addr -> one 256B segment/quad-group) + 4 f4 A-loads +
// 128 FMAs. Butterfly over lane bits 2,3 -> 8KB red LDS -> final reduce,
// rank mask, global write. Peak live ~80 VGPR; no expand phase in-kernel,
// so regalloc cannot hit the 256-VGPR cliff that killed r4-r7.
// ---------------------------------------------------------------------------
__global__ __launch_bounds__(256) void lora_shrink(
    const float* __restrict__ x,
    const float* __restrict__ A,
    const int*   __restrict__ sorted_ids,
    const int*   __restrict__ slot_ranks,
    const int*   __restrict__ slot_offsets,
    float*       __restrict__ inter)
{
    __shared__ float red[4 * 4 * ROWS * MAXR];   // 8 KiB (w,g,j,r)

    const int t  = threadIdx.x;
    const int b  = blockIdx.x;
    const int m  = b >> 9;            // 0..1
    const int i0 = (b & 511) * ROWS;  // row base

    int s = 0;
    #pragma unroll
    for (int k = 1; k < NSLOT; ++k) if (i0 >= slot_offsets[k]) s = k;
    const int R = slot_ranks[s];

    int tok[ROWS];
    #pragma unroll
    for (int j = 0; j < ROWS; ++j) tok[j] = sorted_ids[i0 + j];  // uniform

    const int hq = t >> 2;   // 0..63
    const int q  = t & 3;    // r-quad

    f4 acc[ROWS];
    #pragma unroll
    for (int j = 0; j < ROWS; ++j) acc[j] = (f4)(0.f);

    const float* Ap_base = A + (size_t)(m * NSLOT + s) * (HIDDEN * MAXR);

    #pragma unroll 1
    for (int k = 0; k < 8; ++k) {
        f4 xv[ROWS];
        #pragma unroll
        for (int j = 0; j < ROWS; ++j)
            xv[j] = *(const f4*)(x + (size_t)tok[j] * HIDDEN + 256 * k + 4 * hq);
        const float* Ap = Ap_base + 4096 * k + 64 * hq + 4 * q;
        const f4 a0 = *(const f4*)(Ap);
        const f4 a1 = *(const f4*)(Ap + 16);
        const f4 a2 = *(const f4*)(Ap + 32);
        const f4 a3 = *(const f4*)(Ap + 48);
        #pragma unroll
        for (int j = 0; j < ROWS; ++j) {
            const f4 v = xv[j];
            acc[j] += v.x * a0 + v.y * a1 + v.z * a2 + v.w * a3;
        }
    }

    // butterfly over lane bits 2,3 (low bits of hq)
    #pragma unroll
    for (int j = 0; j < ROWS; ++j) {
        f4 a = acc[j];
        a.x += __shfl_xor(a.x, 4); a.y += __shfl_xor(a.y, 4);
        a.z += __shfl_xor(a.z, 4); a.w += __shfl_xor(a.w, 4);
        a.x += __shfl_xor(a.x, 8); a.y += __shfl_xor(a.y, 8);
        a.z += __shfl_xor(a.z, 8); a.w += __shfl_xor(a.w, 8);
        acc[j] = a;
    }

    if ((t & 12) == 0) {               // lanes 0-3 of each 16-group
        const int w = t >> 6, g = (t >> 4) & 3;
        #pragma unroll
        for (int j = 0; j < ROWS; ++j)
            *(f4*)(red + ((w * 4 + g) * ROWS + j) * MAXR + 4 * q) = acc[j];
    }
    __syncthreads();

    if (t < 128) {   // one (j, r) per thread; sum 16 partials; rank-mask
        const int j = t >> 4, r = t & 15;
        float v = 0.f;
        #pragma unroll
        for (int w = 0; w < 4; ++w)
            #pragma unroll
            for (int g = 0; g < 4; ++g)
                v += red[((w * 4 + g) * ROWS + j) * MAXR + r];
        if (r >= R) v = 0.f;           // rank mask -> expand needs no mask
        inter[((size_t)m * BS + (i0 + j)) * MAXR + r] = v;
    }
}

// ---------------------------------------------------------------------------
// Kernel 2: expand (r2-proven structure). Grid 1024 = (m, s, col-tile rc).
// Each thread caches its 16 x f4 B slab ONCE per block (B L2 traffic 64 MB
// total), then streams 64 rows: uniform inter loads (L1/L2-hit), 16 f4
// FMAs, one coalesced NON-TEMPORAL float4 store per row (output write-once,
// 268 MB >> L2; NT protects B residency). Peak live ~90 VGPR.
// ---------------------------------------------------------------------------
__global__ __launch_bounds__(256) void lora_expand(
    const float* __restrict__ inter,
    const float* __restrict__ B,
    const int*   __restrict__ slot_offsets,
    const int*   __restrict__ slot_counts,
    float*       __restrict__ out)
{
    int b = blockIdx.x;
    const int rc = b & 7; b >>= 3;       // row chunk   (8 x 64 rows)
    const int ct = b & 7; b >>= 3;       // col tile    (8 x 1024 cols)
    const int s  = b & 7; const int m = b >> 3;
    const int t  = threadIdx.x;

    const int row0   = slot_offsets[s] + rc * 64;
    const int rowEnd = slot_offsets[s] + slot_counts[s];
    const int rend   = min(row0 + 64, rowEnd);

    const int c0 = ct * 1024 + t * 4;
    const float* Bp = B + ((size_t)m * NSLOT + s) * MAXR * OUTW + c0;

    f4 breg[MAXR];
    #pragma unroll
    for (int rr = 0; rr < MAXR; ++rr)
        breg[rr] = *(const f4*)(Bp + (size_t)rr * OUTW);

    for (int i = row0; i < rend; ++i) {
        const float* ip = inter + ((size_t)m * BS + i) * MAXR;  // block-uniform
        const f4 w0 = *(const f4*)(ip);
        const f4 w1 = *(const f4*)(ip + 4);
        const f4 w2 = *(const f4*)(ip + 8);
        const f4 w3 = *(const f4*)(ip + 12);
        f4 acc = (f4)(0.f);
        acc += w0.x * breg[0]  + w0.y * breg[1]  + w0.z * breg[2]  + w0.w * breg[3];
        acc += w1.x * breg[4]  + w1.y * breg[5]  + w1.z * breg[6]  + w1.w * breg[7];
        acc += w2.x * breg[8]  + w2.y * breg[9]  + w2.z * breg[10] + w2.w * breg[11];
        acc += w3.x * breg[12] + w3.y * breg[13] + w3.z * breg[14] + w3.w * breg[15];
        __builtin_nontemporal_store(acc,
            (f4*)(out + (size_t)i * (NMOD * OUTW) + (size_t)m * OUTW + c0));
    }
}

extern "C" void kernel_launch(void* const* d_in, const int* in_sizes, int n_in,
                              void* d_out, int out_size, void* d_ws, size_t ws_size,
                              hipStream_t stream)
{
    const float* x            = (const float*)d_in[0];
    const float* A            = (const float*)d_in[1];
    const float* B            = (const float*)d_in[2];
    const int*   sorted_ids   = (const int*)d_in[3];
    const int*   slot_counts  = (const int*)d_in[4];
    const int*   slot_ranks   = (const int*)d_in[5];
    const int*   slot_offsets = (const int*)d_in[6];
    float*       out          = (float*)d_out;
    float*       inter        = (float*)d_ws;   // NMOD*BS*MAXR*4 = 512 KiB

    hipLaunchKernelGGL(lora_shrink, dim3(BS / ROWS * NMOD), dim3(256), 0, stream,
                       x, A, sorted_ids, slot_ranks, slot_offsets, inter);
    hipLaunchKernelGGL(lora_expand, dim3(NMOD * NSLOT * 8 * 8), dim3(256), 0, stream,
                       inter, B, slot_offsets, slot_counts, out);
}

// Round 9
// 84.534 us; speedup vs baseline: 18.3533x; 1.0174x over previous
//
#include <hip/hip_runtime.h>

#define BS     4096
#define HIDDEN 2048
#define MAXR   16
#define NSLOT  8
#define NMOD   2
#define OUTW   8192
#define ROWS   8

typedef float f4 __attribute__((ext_vector_type(4)));

// ---------------------------------------------------------------------------
// Kernel 1: shrink (byte-identical to r8's — proven clean, ~5-10 us).
// Grid 1024 = (m, 8-row chunk). inter[m][i][r] = sum_h x[..][h]*A[m,s,h,r],
// rank-masked so expand needs no mask.
// ---------------------------------------------------------------------------
__global__ __launch_bounds__(256) void lora_shrink(
    const float* __restrict__ x,
    const float* __restrict__ A,
    const int*   __restrict__ sorted_ids,
    const int*   __restrict__ slot_ranks,
    const int*   __restrict__ slot_offsets,
    float*       __restrict__ inter)
{
    __shared__ float red[4 * 4 * ROWS * MAXR];   // 8 KiB (w,g,j,r)

    const int t  = threadIdx.x;
    const int b  = blockIdx.x;
    const int m  = b >> 9;            // 0..1
    const int i0 = (b & 511) * ROWS;  // row base

    int s = 0;
    #pragma unroll
    for (int k = 1; k < NSLOT; ++k) if (i0 >= slot_offsets[k]) s = k;
    const int R = slot_ranks[s];

    int tok[ROWS];
    #pragma unroll
    for (int j = 0; j < ROWS; ++j) tok[j] = sorted_ids[i0 + j];  // uniform

    const int hq = t >> 2;   // 0..63
    const int q  = t & 3;    // r-quad

    f4 acc[ROWS];
    #pragma unroll
    for (int j = 0; j < ROWS; ++j) acc[j] = (f4)(0.f);

    const float* Ap_base = A + (size_t)(m * NSLOT + s) * (HIDDEN * MAXR);

    #pragma unroll 1
    for (int k = 0; k < 8; ++k) {
        f4 xv[ROWS];
        #pragma unroll
        for (int j = 0; j < ROWS; ++j)
            xv[j] = *(const f4*)(x + (size_t)tok[j] * HIDDEN + 256 * k + 4 * hq);
        const float* Ap = Ap_base + 4096 * k + 64 * hq + 4 * q;
        const f4 a0 = *(const f4*)(Ap);
        const f4 a1 = *(const f4*)(Ap + 16);
        const f4 a2 = *(const f4*)(Ap + 32);
        const f4 a3 = *(const f4*)(Ap + 48);
        #pragma unroll
        for (int j = 0; j < ROWS; ++j) {
            const f4 v = xv[j];
            acc[j] += v.x * a0 + v.y * a1 + v.z * a2 + v.w * a3;
        }
    }

    // butterfly over lane bits 2,3 (low bits of hq)
    #pragma unroll
    for (int j = 0; j < ROWS; ++j) {
        f4 a = acc[j];
        a.x += __shfl_xor(a.x, 4); a.y += __shfl_xor(a.y, 4);
        a.z += __shfl_xor(a.z, 4); a.w += __shfl_xor(a.w, 4);
        a.x += __shfl_xor(a.x, 8); a.y += __shfl_xor(a.y, 8);
        a.z += __shfl_xor(a.z, 8); a.w += __shfl_xor(a.w, 8);
        acc[j] = a;
    }

    if ((t & 12) == 0) {               // lanes 0-3 of each 16-group
        const int w = t >> 6, g = (t >> 4) & 3;
        #pragma unroll
        for (int j = 0; j < ROWS; ++j)
            *(f4*)(red + ((w * 4 + g) * ROWS + j) * MAXR + 4 * q) = acc[j];
    }
    __syncthreads();

    if (t < 128) {   // one (j, r) per thread; sum 16 partials; rank-mask
        const int j = t >> 4, r = t & 15;
        float v = 0.f;
        #pragma unroll
        for (int w = 0; w < 4; ++w)
            #pragma unroll
            for (int g = 0; g < 4; ++g)
                v += red[((w * 4 + g) * ROWS + j) * MAXR + r];
        if (r >= R) v = 0.f;           // rank mask -> expand needs no mask
        inter[((size_t)m * BS + (i0 + j)) * MAXR + r] = v;
    }
}

// ---------------------------------------------------------------------------
// Kernel 2: expand. ROUND-9 CHANGES (isolating the ~60-vs-42 us store gap):
//   (1) REGULAR stores, not non-temporal — the only thing measured at
//       6.9 TB/s (harness fill) uses plain stores; NT bypasses L2 write
//       combining. B is 8 MB (L2-resident regardless).
//   (2) 32-row chunks -> grid 2048 (8 blocks/CU): more concurrent store
//       streams, B-slab load latency overlapped by other blocks' stores.
// Everything else identical: breg[16] cached once per block, uniform inter
// loads, coalesced float4 stores.
// ---------------------------------------------------------------------------
__global__ __launch_bounds__(256) void lora_expand(
    const float* __restrict__ inter,
    const float* __restrict__ B,
    const int*   __restrict__ slot_offsets,
    const int*   __restrict__ slot_counts,
    float*       __restrict__ out)
{
    int b = blockIdx.x;
    const int rc = b & 15; b >>= 4;      // row chunk   (16 x 32 rows)
    const int ct = b & 7;  b >>= 3;      // col tile    (8 x 1024 cols)
    const int s  = b & 7;  const int m = b >> 3;
    const int t  = threadIdx.x;

    const int row0   = slot_offsets[s] + rc * 32;
    const int rowEnd = slot_offsets[s] + slot_counts[s];
    const int rend   = min(row0 + 32, rowEnd);

    const int c0 = ct * 1024 + t * 4;
    const float* Bp = B + ((size_t)m * NSLOT + s) * MAXR * OUTW + c0;

    f4 breg[MAXR];
    #pragma unroll
    for (int rr = 0; rr < MAXR; ++rr)
        breg[rr] = *(const f4*)(Bp + (size_t)rr * OUTW);

    for (int i = row0; i < rend; ++i) {
        const float* ip = inter + ((size_t)m * BS + i) * MAXR;  // block-uniform
        const f4 w0 = *(const f4*)(ip);
        const f4 w1 = *(const f4*)(ip + 4);
        const f4 w2 = *(const f4*)(ip + 8);
        const f4 w3 = *(const f4*)(ip + 12);
        f4 acc = (f4)(0.f);
        acc += w0.x * breg[0]  + w0.y * breg[1]  + w0.z * breg[2]  + w0.w * breg[3];
        acc += w1.x * breg[4]  + w1.y * breg[5]  + w1.z * breg[6]  + w1.w * breg[7];
        acc += w2.x * breg[8]  + w2.y * breg[9]  + w2.z * breg[10] + w2.w * breg[11];
        acc += w3.x * breg[12] + w3.y * breg[13] + w3.z * breg[14] + w3.w * breg[15];
        *(f4*)(out + (size_t)i * (NMOD * OUTW) + (size_t)m * OUTW + c0) = acc;
    }
}

extern "C" void kernel_launch(void* const* d_in, const int* in_sizes, int n_in,
                              void* d_out, int out_size, void* d_ws, size_t ws_size,
                              hipStream_t stream)
{
    const float* x            = (const float*)d_in[0];
    const float* A            = (const float*)d_in[1];
    const float* B            = (const float*)d_in[2];
    const int*   sorted_ids   = (const int*)d_in[3];
    const int*   slot_counts  = (const int*)d_in[4];
    const int*   slot_ranks   = (const int*)d_in[5];
    const int*   slot_offsets = (const int*)d_in[6];
    float*       out          = (float*)d_out;
    float*       inter        = (float*)d_ws;   // NMOD*BS*MAXR*4 = 512 KiB

    hipLaunchKernelGGL(lora_shrink, dim3(BS / ROWS * NMOD), dim3(256), 0, stream,
                       x, A, sorted_ids, slot_ranks, slot_offsets, inter);
    hipLaunchKernelGGL(lora_expand, dim3(NMOD * NSLOT * 8 * 16), dim3(256), 0, stream,
                       inter, B, slot_offsets, slot_counts, out);
}